// Round 11
// baseline (306.853 us; speedup 1.0000x reference)
//
#include <hip/hip_runtime.h>
#include <hip/hip_bf16.h>
#include <cstdint>

#define IN_CH 512
#define HC    512   // HEADS*CH
#define HEADS 8
#define NPACK 1024  // W_l | W_r packed

typedef __attribute__((ext_vector_type(8))) short bf16x8;
typedef __attribute__((ext_vector_type(8))) ushort u16x8;
typedef __attribute__((ext_vector_type(4))) float f32x4;
typedef const __attribute__((address_space(1))) uint8_t* gaddr_t;
typedef __attribute__((address_space(3))) uint8_t* laddr_t;

__device__ inline ushort f2bf(float f) {  // round-to-nearest-even
  uint32_t u = __float_as_uint(f);
  return (ushort)((u + 0x7fffu + ((u >> 16) & 1u)) >> 16);
}
__device__ inline float bf2f(ushort u) {
  return __uint_as_float(((uint32_t)u) << 16);
}

// ---- fused prep: cast x->bf16 | pack W^T bf16 | hist(dst) | hist(label s) --
__global__ void prep(const float* __restrict__ x, ushort* __restrict__ xb,
                     const float* __restrict__ Wl, const float* __restrict__ Wr,
                     ushort* __restrict__ bt,
                     const int* __restrict__ ei, int* __restrict__ counts,
                     const int* __restrict__ eli, int* __restrict__ counts2,
                     int n4, int E, int EL, int nbc, int nbp, int nbh) {
  const int b = blockIdx.x;
  if (b < nbc) {
    const int i = b * 256 + threadIdx.x;
    if (i < n4) {
      const float4 v = ((const float4*)x)[i];
      ushort4 o;
      o.x = f2bf(v.x); o.y = f2bf(v.y); o.z = f2bf(v.z); o.w = f2bf(v.w);
      ((ushort4*)xb)[i] = o;
    }
  } else if (b < nbc + nbp) {
    const int i = (b - nbc) * 256 + threadIdx.x;
    if (i < NPACK * IN_CH) {
      const int n = i >> 9, k = i & 511;
      const float v = (n < HC) ? Wl[(size_t)k * HC + n] : Wr[(size_t)k * HC + (n - HC)];
      bt[i] = f2bf(v);
    }
  } else if (b < nbc + nbp + nbh) {
    const int e = (b - nbc - nbp) * 256 + threadIdx.x;
    if (e < E) atomicAdd(&counts[ei[E + e]], 1);
  } else {
    const int e = (b - nbc - nbp - nbh) * 256 + threadIdx.x;
    if (e < EL) atomicAdd(&counts2[eli[e]], 1);
  }
}

// ---- bf16 MFMA GEMM: [M,1024] = xb[M,512] @ Bt^T -> xlb | xrb (both bf16) --
__global__ __launch_bounds__(256) void gemm_mfma(
    const ushort* __restrict__ xb, const ushort* __restrict__ bt,
    ushort* __restrict__ xlb, ushort* __restrict__ xrb, int M) {
  __shared__ __align__(16) ushort As[128 * 32];  // [row][k], stride 32
  __shared__ __align__(16) ushort Bs[128 * 32];  // [col][k], stride 32
  const int wave = threadIdx.x >> 6, lane = threadIdx.x & 63;
  const int row0 = blockIdx.y * 128, col0 = blockIdx.x * 128;
  const int quad = lane >> 4, m16 = lane & 15;
  const int wrow = (wave >> 1) * 64, wcol = (wave & 1) * 64;
  const int srow = lane >> 2;
  const int scol = (lane & 3) * 8;
  const f32x4 zero = {0.f, 0.f, 0.f, 0.f};
  f32x4 acc[4][4];
  #pragma unroll
  for (int i = 0; i < 4; ++i)
    #pragma unroll
    for (int j = 0; j < 4; ++j) acc[i][j] = zero;

  for (int k0 = 0; k0 < IN_CH; k0 += 32) {
    #pragma unroll
    for (int c = 0; c < 2; ++c) {
      const int chunk = wave * 2 + c;
      const ushort* ga = xb + (size_t)(row0 + chunk * 16 + srow) * IN_CH + k0 + scol;
      __builtin_amdgcn_global_load_lds((gaddr_t)ga, (laddr_t)(As + chunk * 512), 16, 0, 0);
      const ushort* gb = bt + (size_t)(col0 + chunk * 16 + srow) * IN_CH + k0 + scol;
      __builtin_amdgcn_global_load_lds((gaddr_t)gb, (laddr_t)(Bs + chunk * 512), 16, 0, 0);
    }
    __syncthreads();
    bf16x8 af[4], bfr[4];
    #pragma unroll
    for (int i = 0; i < 4; ++i)
      af[i] = *(const bf16x8*)(As + (wrow + i * 16 + m16) * 32 + quad * 8);
    #pragma unroll
    for (int j = 0; j < 4; ++j)
      bfr[j] = *(const bf16x8*)(Bs + (wcol + j * 16 + m16) * 32 + quad * 8);
    #pragma unroll
    for (int i = 0; i < 4; ++i)
      #pragma unroll
      for (int j = 0; j < 4; ++j)
        acc[i][j] = __builtin_amdgcn_mfma_f32_16x16x32_bf16(af[i], bfr[j], acc[i][j], 0, 0, 0);
    __syncthreads();
  }
  const bool isL = (col0 < HC);
  ushort* dst = isL ? xlb : xrb;
  const int cbase = isL ? col0 : (col0 - HC);
  #pragma unroll
  for (int i = 0; i < 4; ++i) {
    const int r = row0 + wrow + i * 16 + quad * 4;
    #pragma unroll
    for (int j = 0; j < 4; ++j) {
      const int cg = cbase + wcol + j * 16 + m16;
      #pragma unroll
      for (int t = 0; t < 4; ++t) {
        const int rr = r + t;
        if (rr < M) dst[(size_t)rr * HC + cg] = f2bf(acc[i][j][t]);
      }
    }
  }
}

// ---- fused dual-CSR scan + fill (one dispatch) -----------------------------
// Phase A: per-block scan + lookback prefix (R10-proven). Cursor init uses
// device-scope atomicExch so phase-B atomics on other XCDs see the values
// (plain stores are NOT cross-XCD coherent within one kernel).
// Barrier: every block publishes to `done` BEFORE spinning; all 2*nb=158
// blocks are trivially co-resident -> deadlock-free.
// Phase B: grid-stride fill of both CSRs.
__global__ __launch_bounds__(256) void scan_fill(
    const int* __restrict__ cA, int* __restrict__ oA, int* __restrict__ curA,
    int* __restrict__ fA,
    const int* __restrict__ cB, int* __restrict__ oB, int* __restrict__ curB,
    int* __restrict__ fB, int* __restrict__ done,
    const int* __restrict__ ei, int* __restrict__ csr_src,
    const int* __restrict__ eli, int* __restrict__ csr_t, int* __restrict__ csr_eid,
    int Nn, int nb, int E, int EL) {
  const int half = (blockIdx.x >= nb) ? 1 : 0;
  const int blk  = blockIdx.x - half * nb;
  const int* counts = half ? cB : cA;
  int* offsets = half ? oB : oA;
  int* cursor  = half ? curB : curA;
  int* flags   = half ? fB : fA;
  __shared__ int tmp[256];
  __shared__ int sPref;
  const int t = threadIdx.x;
  const int i = blk * 256 + t;
  const int v = (i < Nn) ? counts[i] : 0;
  tmp[t] = v;
  __syncthreads();
  for (int d = 1; d < 256; d <<= 1) {
    int add = (t >= d) ? tmp[t - d] : 0;
    __syncthreads();
    tmp[t] += add;
    __syncthreads();
  }
  if (t == 0) atomicExch(&flags[blk], tmp[255] + 1);  // publish aggregate
  if (t < 64) {
    int s = 0;
    for (int b = t; b < blk; b += 64) {
      int f;
      do { f = atomicOr(&flags[b], 0); } while (f == 0);
      s += f - 1;
    }
    #pragma unroll
    for (int off = 32; off > 0; off >>= 1) s += __shfl_down(s, off, 64);
    if (t == 0) sPref = s;
  }
  __syncthreads();
  if (i < Nn) {
    const int o = tmp[t] - v + sPref;  // exclusive prefix
    offsets[i] = o;                    // consumed by later kernels (flushed)
    atomicExch(&cursor[i], o);         // consumed by phase B cross-XCD
  }
  // ---- all-resident device barrier ----
  __threadfence();
  __syncthreads();
  if (t == 0) {
    atomicAdd(done, 1);
    while (atomicOr(done, 0) < 2 * nb) {}
  }
  __syncthreads();
  // ---- phase B: grid-stride fill of both CSRs ----
  const int nthreads = 2 * nb * 256;
  const int total = E + EL;
  for (int e = blockIdx.x * 256 + t; e < total; e += nthreads) {
    if (e < E) {
      const int pos = atomicAdd(&curA[ei[E + e]], 1);
      csr_src[pos] = ei[e];
    } else {
      const int e2 = e - E;
      const int pos = atomicAdd(&curB[eli[e2]], 1);
      csr_t[pos] = eli[EL + e2];
      csr_eid[pos] = e2;
    }
  }
}

// ------- fused GATv2: logits + softmax + aggregation, 1 wave/node -----------
// R8-proven config: 16 B/lane bf16 gathers, prefetch-2, bf16 xr/agg.
// Gather indices scalarized (readfirstlane) -> address math on SALU.
__global__ __launch_bounds__(256) void gatv2_agg(
    const ushort* __restrict__ xlb, const ushort* xrb, const float* __restrict__ att,
    const int* __restrict__ offsets, const int* __restrict__ counts,
    const int* __restrict__ csr_src, ushort* agg, int Nn) {
  const int node = blockIdx.x * 4 + (threadIdx.x >> 6);
  const int lane = threadIdx.x & 63;
  if (node >= Nn) return;
  const int start = offsets[node];
  const int deg   = counts[node];
  float rv[8], tv[8];
  {
    const u16x8 ur = *(const u16x8*)(xrb + (size_t)node * HC + lane * 8);
    #pragma unroll
    for (int c = 0; c < 8; ++c) rv[c] = bf2f((ushort)ur[c]);
    const float4* pa = (const float4*)(att + lane * 8);
    const float4 t0 = pa[0], t1 = pa[1];
    tv[0]=t0.x; tv[1]=t0.y; tv[2]=t0.z; tv[3]=t0.w;
    tv[4]=t1.x; tv[5]=t1.y; tv[6]=t1.z; tv[7]=t1.w;
  }
  float acc[8] = {};
  float densum = 0.f;
  const int* ps = csr_src + start;
  auto row = [&](int idx) {
    const int src = __builtin_amdgcn_readfirstlane(ps[idx]);  // wave-uniform
    return *(const u16x8*)(xlb + (size_t)src * HC + lane * 8);
  };
  auto body = [&](const u16x8 cur) {
    float a[8];
    #pragma unroll
    for (int c = 0; c < 8; ++c) a[c] = bf2f((ushort)cur[c]);
    float s = 0.f;
    #pragma unroll
    for (int c = 0; c < 8; ++c) {
      const float v = a[c] + rv[c];
      s += fmaxf(v, 0.2f * v) * tv[c];  // leaky_relu(v,0.2) == max(v,0.2v)
    }
    s += __shfl_xor(s, 1, 8);
    s += __shfl_xor(s, 2, 8);
    s += __shfl_xor(s, 4, 8);
    const float ea = __expf(s);
    densum += ea;
    #pragma unroll
    for (int c = 0; c < 8; ++c) acc[c] += ea * a[c];
  };

  u16x8 b0 = {}, b1 = {};
  if (deg > 0) b0 = row(0);
  if (deg > 1) b1 = row(1);
  int i = 0;
  for (; i + 2 <= deg; i += 2) {
    const u16x8 c0 = b0;
    if (i + 2 < deg) b0 = row(i + 2);
    const u16x8 c1 = b1;
    if (i + 3 < deg) b1 = row(i + 3);
    body(c0);
    body(c1);
  }
  if (i < deg) body(b0);

  const float inv = 1.0f / (densum + 1e-16f);
  ushort* pd = agg + (size_t)node * HC + lane * 8;
  ushort4 o0, o1;
  o0.x = f2bf(acc[0] * inv); o0.y = f2bf(acc[1] * inv);
  o0.z = f2bf(acc[2] * inv); o0.w = f2bf(acc[3] * inv);
  o1.x = f2bf(acc[4] * inv); o1.y = f2bf(acc[5] * inv);
  o1.z = f2bf(acc[6] * inv); o1.w = f2bf(acc[7] * inv);
  *(ushort4*)(pd + 0) = o0;
  *(ushort4*)(pd + 4) = o1;
}

// ------------- BatchNorm stats + last-block finalize ------------------------
__global__ void bn_stats(const ushort* __restrict__ agg, float* __restrict__ gsum,
                         float* __restrict__ gsq, int* __restrict__ ctr,
                         const float* __restrict__ gamma, const float* __restrict__ beta,
                         float* __restrict__ aScale, float* __restrict__ bShift,
                         float invN, int Nn) {
  const int t = threadIdx.x;  // 256; thread covers channels 2t, 2t+1
  const int rows_per_block = (Nn + gridDim.x - 1) / gridDim.x;
  const int r0 = blockIdx.x * rows_per_block;
  const int r1 = min(Nn, r0 + rows_per_block);
  float s0 = 0.f, s1 = 0.f, q0 = 0.f, q1 = 0.f;
  for (int r = r0; r < r1; ++r) {
    const ushort2 u = ((const ushort2*)(agg + (size_t)r * HC))[t];
    const float v0 = bf2f(u.x), v1 = bf2f(u.y);
    s0 += v0; q0 += v0 * v0;
    s1 += v1; q1 += v1 * v1;
  }
  atomicAdd(&gsum[2 * t], s0);
  atomicAdd(&gsum[2 * t + 1], s1);
  atomicAdd(&gsq[2 * t], q0);
  atomicAdd(&gsq[2 * t + 1], q1);
  __shared__ int isLast;
  __syncthreads();
  if (t == 0) {
    __threadfence();
    isLast = (atomicAdd(ctr, 1) == (int)gridDim.x - 1) ? 1 : 0;
  }
  __syncthreads();
  if (isLast) {
    #pragma unroll
    for (int k = 0; k < 2; ++k) {
      const int c = t + k * 256;
      const float sum = atomicAdd(&gsum[c], 0.0f);  // coherent read
      const float sq  = atomicAdd(&gsq[c], 0.0f);
      const float m = sum * invN;
      const float var = sq * invN - m * m;
      const float rs = rsqrtf(var + 1e-5f);
      const float a = rs * gamma[c];
      aScale[c] = a;
      bShift[c] = beta[c] - m * a;
    }
  }
}

// ------------- source-grouped link scoring with inline BN+ReLU --------------
__global__ __launch_bounds__(256) void score_g(
    const ushort* __restrict__ agg, const float* __restrict__ aScale,
    const float* __restrict__ bShift, const int* __restrict__ off2,
    const int* __restrict__ cnt2, const int* __restrict__ csr_t,
    const int* __restrict__ csr_eid, float* __restrict__ out, int Nn) {
  const int node = blockIdx.x * 4 + (threadIdx.x >> 6);
  const int lane = threadIdx.x & 63;
  if (node >= Nn) return;
  const int start = off2[node];
  const int deg   = cnt2[node];
  if (deg == 0) return;
  float aS[8], bS[8], ys[8];
  {
    const float4* pa = (const float4*)(aScale + lane * 8);
    const float4 a0 = pa[0], a1 = pa[1];
    aS[0]=a0.x; aS[1]=a0.y; aS[2]=a0.z; aS[3]=a0.w;
    aS[4]=a1.x; aS[5]=a1.y; aS[6]=a1.z; aS[7]=a1.w;
    const float4* pb = (const float4*)(bShift + lane * 8);
    const float4 c0 = pb[0], c1 = pb[1];
    bS[0]=c0.x; bS[1]=c0.y; bS[2]=c0.z; bS[3]=c0.w;
    bS[4]=c1.x; bS[5]=c1.y; bS[6]=c1.z; bS[7]=c1.w;
    const u16x8 us = *(const u16x8*)(agg + (size_t)node * HC + lane * 8);
    #pragma unroll
    for (int c = 0; c < 8; ++c)
      ys[c] = fmaxf(0.f, bf2f((ushort)us[c]) * aS[c] + bS[c]);
  }
  const int* pt = csr_t + start;
  const int* pe = csr_eid + start;
  auto row = [&](int idx) {
    const int tgt = __builtin_amdgcn_readfirstlane(pt[idx]);  // wave-uniform
    return *(const u16x8*)(agg + (size_t)tgt * HC + lane * 8);
  };
  auto emit = [&](const u16x8 ut, int eid) {
    float s = 0.f;
    #pragma unroll
    for (int c = 0; c < 8; ++c)
      s += ys[c] * fmaxf(0.f, bf2f((ushort)ut[c]) * aS[c] + bS[c]);
    #pragma unroll
    for (int off = 32; off > 0; off >>= 1) s += __shfl_down(s, off, 64);
    if (lane == 0) out[eid] = s;
  };
  u16x8 b0 = {}, b1 = {};
  b0 = row(0);
  if (deg > 1) b1 = row(1);
  int j = 0;
  for (; j + 2 <= deg; j += 2) {
    const u16x8 c0 = b0;
    if (j + 2 < deg) b0 = row(j + 2);
    const u16x8 c1 = b1;
    if (j + 3 < deg) b1 = row(j + 3);
    emit(c0, __builtin_amdgcn_readfirstlane(pe[j]));
    emit(c1, __builtin_amdgcn_readfirstlane(pe[j + 1]));
  }
  if (j < deg) emit(b0, __builtin_amdgcn_readfirstlane(pe[j]));
}

extern "C" void kernel_launch(void* const* d_in, const int* in_sizes, int n_in,
                              void* d_out, int out_size, void* d_ws, size_t ws_size,
                              hipStream_t stream) {
  const float* x     = (const float*)d_in[0];
  const int*   ei    = (const int*)d_in[1];
  const int*   eli   = (const int*)d_in[2];
  const float* W_l   = (const float*)d_in[3];
  const float* W_r   = (const float*)d_in[4];
  const float* att   = (const float*)d_in[5];
  // d_in[6] = bias: cancels exactly inside train-mode BatchNorm -> unused.
  const float* gamma = (const float*)d_in[7];
  const float* beta  = (const float*)d_in[8];
  float* out = (float*)d_out;

  const int Nn = in_sizes[0] / IN_CH;  // 20000
  const int E  = in_sizes[1] / 2;      // 320000
  const int EL = in_sizes[2] / 2;      // 100000

  // ---- workspace layout ----
  ushort* xlb = (ushort*)d_ws;                     // Nn*HC bf16
  ushort* xrb = xlb + (size_t)Nn * HC;             // Nn*HC bf16 (reused as agg)
  ushort* xbf = xrb + (size_t)Nn * HC;             // Nn*IN_CH bf16
  ushort* btb = xbf + (size_t)Nn * IN_CH;          // NPACK*IN_CH bf16
  int* counts   = (int*)(btb + (size_t)NPACK * IN_CH);  // Nn ┐
  int* counts2  = counts + Nn;                          // Nn │ single
  float* gsum   = (float*)(counts2 + Nn);               // HC │ memset
  float* gsq    = gsum + HC;                            // HC │ region
  int* flagsA   = (int*)(gsq + HC);                     // 128│
  int* flagsB   = flagsA + 128;                         // 128│
  int* bnctr    = flagsB + 128;                         // 64 │
  int* done     = bnctr + 64;                           // 64 ┘ (padded)
  int* offsets  = done + 64;            // Nn
  int* cursor   = offsets + Nn;         // Nn
  int* offsets2 = cursor + Nn;          // Nn
  int* cursor2  = offsets2 + Nn;        // Nn
  int* csr_src  = cursor2 + Nn;         // E
  int* csr_t    = csr_src + E;          // EL
  int* csr_eid  = csr_t + EL;           // EL
  float* aScale = (float*)(csr_eid + EL);  // HC
  float* bShift = aScale + HC;             // HC
  ushort* agg = xrb;

  const int nb  = (Nn + 255) / 256;           // scan blocks per CSR (79)
  const int nbc = (Nn * IN_CH / 4 + 255) / 256;
  const int nbp = (NPACK * IN_CH + 255) / 256;
  const int nbh = (E + 255) / 256;
  const int nbh2 = (EL + 255) / 256;

  // 0) one memset: counts | counts2 | gsum | gsq | flagsA | flagsB | bnctr | done
  (void)hipMemsetAsync(counts, 0, (2 * (size_t)Nn + 2 * HC + 384) * sizeof(int), stream);

  // 1) fused prep: cast + pack + both histograms
  prep<<<nbc + nbp + nbh + nbh2, 256, 0, stream>>>(
      x, xbf, W_l, W_r, btb, ei, counts, eli, counts2,
      Nn * IN_CH / 4, E, EL, nbc, nbp, nbh);

  // 2) one bf16 MFMA GEMM -> xlb | xrb
  dim3 ggrid(NPACK / 128, (Nn + 127) / 128);
  gemm_mfma<<<ggrid, 256, 0, stream>>>(xbf, btb, xlb, xrb, Nn);

  // 3) fused dual-CSR scan + in-kernel barrier + fill (one dispatch)
  scan_fill<<<2 * nb, 256, 0, stream>>>(counts, offsets, cursor, flagsA,
                                        counts2, offsets2, cursor2, flagsB, done,
                                        ei, csr_src, eli, csr_t, csr_eid,
                                        Nn, nb, E, EL);

  // 4) fused attention + softmax + aggregation (1 wave/node, no atomics)
  gatv2_agg<<<(Nn + 3) / 4, 256, 0, stream>>>(xlb, xrb, att, offsets, counts,
                                              csr_src, agg, Nn);

  // 5) BN stats + last-block finalize -> aScale/bShift
  bn_stats<<<200, 256, 0, stream>>>(agg, gsum, gsq, bnctr, gamma, beta,
                                    aScale, bShift, 1.0f / (float)Nn, Nn);

  // 6) source-grouped link scoring with inline BN+ReLU
  score_g<<<(Nn + 3) / 4, 256, 0, stream>>>(agg, aScale, bShift, offsets2,
                                            counts2, csr_t, csr_eid, out, Nn);
}

// Round 12
// 298.408 us; speedup vs baseline: 1.0283x; 1.0283x over previous
//
#include <hip/hip_runtime.h>
#include <hip/hip_bf16.h>
#include <cstdint>

#define IN_CH 512
#define HC    512   // HEADS*CH
#define HEADS 8
#define NPACK 1024  // W_l | W_r packed

typedef __attribute__((ext_vector_type(8))) short bf16x8;
typedef __attribute__((ext_vector_type(8))) ushort u16x8;
typedef __attribute__((ext_vector_type(4))) float f32x4;
typedef const __attribute__((address_space(1))) uint8_t* gaddr_t;
typedef __attribute__((address_space(3))) uint8_t* laddr_t;

__device__ inline ushort f2bf(float f) {  // round-to-nearest-even
  uint32_t u = __float_as_uint(f);
  return (ushort)((u + 0x7fffu + ((u >> 16) & 1u)) >> 16);
}
__device__ inline float bf2f(ushort u) {
  return __uint_as_float(((uint32_t)u) << 16);
}

// ---- fused prep: cast x->bf16 | pack W^T bf16 | hist(dst) | hist(label s) --
__global__ void prep(const float* __restrict__ x, ushort* __restrict__ xb,
                     const float* __restrict__ Wl, const float* __restrict__ Wr,
                     ushort* __restrict__ bt,
                     const int* __restrict__ ei, int* __restrict__ counts,
                     const int* __restrict__ eli, int* __restrict__ counts2,
                     int n4, int E, int EL, int nbc, int nbp, int nbh) {
  const int b = blockIdx.x;
  if (b < nbc) {
    const int i = b * 256 + threadIdx.x;
    if (i < n4) {
      const float4 v = ((const float4*)x)[i];
      ushort4 o;
      o.x = f2bf(v.x); o.y = f2bf(v.y); o.z = f2bf(v.z); o.w = f2bf(v.w);
      ((ushort4*)xb)[i] = o;
    }
  } else if (b < nbc + nbp) {
    const int i = (b - nbc) * 256 + threadIdx.x;
    if (i < NPACK * IN_CH) {
      const int n = i >> 9, k = i & 511;
      const float v = (n < HC) ? Wl[(size_t)k * HC + n] : Wr[(size_t)k * HC + (n - HC)];
      bt[i] = f2bf(v);
    }
  } else if (b < nbc + nbp + nbh) {
    const int e = (b - nbc - nbp) * 256 + threadIdx.x;
    if (e < E) atomicAdd(&counts[ei[E + e]], 1);
  } else {
    const int e = (b - nbc - nbp - nbh) * 256 + threadIdx.x;
    if (e < EL) atomicAdd(&counts2[eli[e]], 1);
  }
}

// ---- bf16 MFMA GEMM: [M,1024] = xb[M,512] @ Bt^T -> xlb | xrb (both bf16) --
__global__ __launch_bounds__(256) void gemm_mfma(
    const ushort* __restrict__ xb, const ushort* __restrict__ bt,
    ushort* __restrict__ xlb, ushort* __restrict__ xrb, int M) {
  __shared__ __align__(16) ushort As[128 * 32];  // [row][k], stride 32
  __shared__ __align__(16) ushort Bs[128 * 32];  // [col][k], stride 32
  const int wave = threadIdx.x >> 6, lane = threadIdx.x & 63;
  const int row0 = blockIdx.y * 128, col0 = blockIdx.x * 128;
  const int quad = lane >> 4, m16 = lane & 15;
  const int wrow = (wave >> 1) * 64, wcol = (wave & 1) * 64;
  const int srow = lane >> 2;
  const int scol = (lane & 3) * 8;
  const f32x4 zero = {0.f, 0.f, 0.f, 0.f};
  f32x4 acc[4][4];
  #pragma unroll
  for (int i = 0; i < 4; ++i)
    #pragma unroll
    for (int j = 0; j < 4; ++j) acc[i][j] = zero;

  for (int k0 = 0; k0 < IN_CH; k0 += 32) {
    #pragma unroll
    for (int c = 0; c < 2; ++c) {
      const int chunk = wave * 2 + c;
      const ushort* ga = xb + (size_t)(row0 + chunk * 16 + srow) * IN_CH + k0 + scol;
      __builtin_amdgcn_global_load_lds((gaddr_t)ga, (laddr_t)(As + chunk * 512), 16, 0, 0);
      const ushort* gb = bt + (size_t)(col0 + chunk * 16 + srow) * IN_CH + k0 + scol;
      __builtin_amdgcn_global_load_lds((gaddr_t)gb, (laddr_t)(Bs + chunk * 512), 16, 0, 0);
    }
    __syncthreads();
    bf16x8 af[4], bfr[4];
    #pragma unroll
    for (int i = 0; i < 4; ++i)
      af[i] = *(const bf16x8*)(As + (wrow + i * 16 + m16) * 32 + quad * 8);
    #pragma unroll
    for (int j = 0; j < 4; ++j)
      bfr[j] = *(const bf16x8*)(Bs + (wcol + j * 16 + m16) * 32 + quad * 8);
    #pragma unroll
    for (int i = 0; i < 4; ++i)
      #pragma unroll
      for (int j = 0; j < 4; ++j)
        acc[i][j] = __builtin_amdgcn_mfma_f32_16x16x32_bf16(af[i], bfr[j], acc[i][j], 0, 0, 0);
    __syncthreads();
  }
  const bool isL = (col0 < HC);
  ushort* dst = isL ? xlb : xrb;
  const int cbase = isL ? col0 : (col0 - HC);
  #pragma unroll
  for (int i = 0; i < 4; ++i) {
    const int r = row0 + wrow + i * 16 + quad * 4;
    #pragma unroll
    for (int j = 0; j < 4; ++j) {
      const int cg = cbase + wcol + j * 16 + m16;
      #pragma unroll
      for (int t = 0; t < 4; ++t) {
        const int rr = r + t;
        if (rr < M) dst[(size_t)rr * HC + cg] = f2bf(acc[i][j][t]);
      }
    }
  }
}

// ---- fused dual-CSR exclusive scan (R10-proven lookback version) -----------
__global__ __launch_bounds__(256) void scan_fused(
    const int* __restrict__ cA, int* __restrict__ oA, int* __restrict__ curA,
    int* __restrict__ fA,
    const int* __restrict__ cB, int* __restrict__ oB, int* __restrict__ curB,
    int* __restrict__ fB, int Nn, int nb) {
  const int half = (blockIdx.x >= nb) ? 1 : 0;
  const int blk  = blockIdx.x - half * nb;
  const int* counts = half ? cB : cA;
  int* offsets = half ? oB : oA;
  int* cursor  = half ? curB : curA;
  int* flags   = half ? fB : fA;
  __shared__ int tmp[256];
  __shared__ int sPref;
  const int t = threadIdx.x;
  const int i = blk * 256 + t;
  const int v = (i < Nn) ? counts[i] : 0;
  tmp[t] = v;
  __syncthreads();
  for (int d = 1; d < 256; d <<= 1) {
    int add = (t >= d) ? tmp[t - d] : 0;
    __syncthreads();
    tmp[t] += add;
    __syncthreads();
  }
  if (t == 0) atomicExch(&flags[blk], tmp[255] + 1);  // publish aggregate
  if (t < 64) {
    int s = 0;
    for (int b = t; b < blk; b += 64) {
      int f;
      do { f = atomicOr(&flags[b], 0); } while (f == 0);
      s += f - 1;
    }
    #pragma unroll
    for (int off = 32; off > 0; off >>= 1) s += __shfl_down(s, off, 64);
    if (t == 0) sPref = s;
  }
  __syncthreads();
  const int pref = sPref;
  if (i < Nn) {
    const int o = tmp[t] - v + pref;  // exclusive prefix
    offsets[i] = o;
    cursor[i] = o;
  }
}

__global__ void csr_fill(const int* __restrict__ ei, int* __restrict__ cursor,
                         int* __restrict__ csr_src,
                         const int* __restrict__ eli, int* __restrict__ cursor2,
                         int* __restrict__ csr_t, int* __restrict__ csr_eid,
                         int E, int EL, int nbE) {
  const int b = blockIdx.x;
  if (b < nbE) {
    const int e = b * 256 + threadIdx.x;
    if (e < E) {
      const int pos = atomicAdd(&cursor[ei[E + e]], 1);
      csr_src[pos] = ei[e];
    }
  } else {
    const int e = (b - nbE) * 256 + threadIdx.x;
    if (e < EL) {
      const int pos = atomicAdd(&cursor2[eli[e]], 1);
      csr_t[pos] = eli[EL + e];
      csr_eid[pos] = e;
    }
  }
}

// ------- fused GATv2: logits + softmax + aggregation, 1 wave/node -----------
// R8/R10-proven config: 16 B/lane bf16 gathers, prefetch-2, bf16 xr/agg,
// plain vector index loads (readfirstlane measured as a regression in R11).
__global__ __launch_bounds__(256) void gatv2_agg(
    const ushort* __restrict__ xlb, const ushort* xrb, const float* __restrict__ att,
    const int* __restrict__ offsets, const int* __restrict__ counts,
    const int* __restrict__ csr_src, ushort* agg, int Nn) {
  const int node = blockIdx.x * 4 + (threadIdx.x >> 6);
  const int lane = threadIdx.x & 63;
  if (node >= Nn) return;
  const int start = offsets[node];
  const int deg   = counts[node];
  float rv[8], tv[8];
  {
    const u16x8 ur = *(const u16x8*)(xrb + (size_t)node * HC + lane * 8);
    #pragma unroll
    for (int c = 0; c < 8; ++c) rv[c] = bf2f((ushort)ur[c]);
    const float4* pa = (const float4*)(att + lane * 8);
    const float4 t0 = pa[0], t1 = pa[1];
    tv[0]=t0.x; tv[1]=t0.y; tv[2]=t0.z; tv[3]=t0.w;
    tv[4]=t1.x; tv[5]=t1.y; tv[6]=t1.z; tv[7]=t1.w;
  }
  float acc[8] = {};
  float densum = 0.f;
  const int* ps = csr_src + start;
  auto row = [&](int idx) {
    return *(const u16x8*)(xlb + (size_t)ps[idx] * HC + lane * 8);
  };
  auto body = [&](const u16x8 cur) {
    float a[8];
    #pragma unroll
    for (int c = 0; c < 8; ++c) a[c] = bf2f((ushort)cur[c]);
    float s = 0.f;
    #pragma unroll
    for (int c = 0; c < 8; ++c) {
      const float v = a[c] + rv[c];
      s += fmaxf(v, 0.2f * v) * tv[c];  // leaky_relu(v,0.2) == max(v,0.2v)
    }
    s += __shfl_xor(s, 1, 8);
    s += __shfl_xor(s, 2, 8);
    s += __shfl_xor(s, 4, 8);
    const float ea = __expf(s);
    densum += ea;
    #pragma unroll
    for (int c = 0; c < 8; ++c) acc[c] += ea * a[c];
  };

  u16x8 b0 = {}, b1 = {};
  if (deg > 0) b0 = row(0);
  if (deg > 1) b1 = row(1);
  int i = 0;
  for (; i + 2 <= deg; i += 2) {
    const u16x8 c0 = b0;
    if (i + 2 < deg) b0 = row(i + 2);
    const u16x8 c1 = b1;
    if (i + 3 < deg) b1 = row(i + 3);
    body(c0);
    body(c1);
  }
  if (i < deg) body(b0);

  const float inv = 1.0f / (densum + 1e-16f);
  ushort* pd = agg + (size_t)node * HC + lane * 8;
  ushort4 o0, o1;
  o0.x = f2bf(acc[0] * inv); o0.y = f2bf(acc[1] * inv);
  o0.z = f2bf(acc[2] * inv); o0.w = f2bf(acc[3] * inv);
  o1.x = f2bf(acc[4] * inv); o1.y = f2bf(acc[5] * inv);
  o1.z = f2bf(acc[6] * inv); o1.w = f2bf(acc[7] * inv);
  *(ushort4*)(pd + 0) = o0;
  *(ushort4*)(pd + 4) = o1;
}

// ------------- BatchNorm stats + last-block finalize ------------------------
__global__ void bn_stats(const ushort* __restrict__ agg, float* __restrict__ gsum,
                         float* __restrict__ gsq, int* __restrict__ ctr,
                         const float* __restrict__ gamma, const float* __restrict__ beta,
                         float* __restrict__ aScale, float* __restrict__ bShift,
                         float invN, int Nn) {
  const int t = threadIdx.x;  // 256; thread covers channels 2t, 2t+1
  const int rows_per_block = (Nn + gridDim.x - 1) / gridDim.x;
  const int r0 = blockIdx.x * rows_per_block;
  const int r1 = min(Nn, r0 + rows_per_block);
  float s0 = 0.f, s1 = 0.f, q0 = 0.f, q1 = 0.f;
  for (int r = r0; r < r1; ++r) {
    const ushort2 u = ((const ushort2*)(agg + (size_t)r * HC))[t];
    const float v0 = bf2f(u.x), v1 = bf2f(u.y);
    s0 += v0; q0 += v0 * v0;
    s1 += v1; q1 += v1 * v1;
  }
  atomicAdd(&gsum[2 * t], s0);
  atomicAdd(&gsum[2 * t + 1], s1);
  atomicAdd(&gsq[2 * t], q0);
  atomicAdd(&gsq[2 * t + 1], q1);
  __shared__ int isLast;
  __syncthreads();
  if (t == 0) {
    __threadfence();
    isLast = (atomicAdd(ctr, 1) == (int)gridDim.x - 1) ? 1 : 0;
  }
  __syncthreads();
  if (isLast) {
    #pragma unroll
    for (int k = 0; k < 2; ++k) {
      const int c = t + k * 256;
      const float sum = atomicAdd(&gsum[c], 0.0f);  // coherent read
      const float sq  = atomicAdd(&gsq[c], 0.0f);
      const float m = sum * invN;
      const float var = sq * invN - m * m;
      const float rs = rsqrtf(var + 1e-5f);
      const float a = rs * gamma[c];
      aScale[c] = a;
      bShift[c] = beta[c] - m * a;
    }
  }
}

// ------------- source-grouped link scoring with inline BN+ReLU --------------
__global__ __launch_bounds__(256) void score_g(
    const ushort* __restrict__ agg, const float* __restrict__ aScale,
    const float* __restrict__ bShift, const int* __restrict__ off2,
    const int* __restrict__ cnt2, const int* __restrict__ csr_t,
    const int* __restrict__ csr_eid, float* __restrict__ out, int Nn) {
  const int node = blockIdx.x * 4 + (threadIdx.x >> 6);
  const int lane = threadIdx.x & 63;
  if (node >= Nn) return;
  const int start = off2[node];
  const int deg   = cnt2[node];
  if (deg == 0) return;
  float aS[8], bS[8], ys[8];
  {
    const float4* pa = (const float4*)(aScale + lane * 8);
    const float4 a0 = pa[0], a1 = pa[1];
    aS[0]=a0.x; aS[1]=a0.y; aS[2]=a0.z; aS[3]=a0.w;
    aS[4]=a1.x; aS[5]=a1.y; aS[6]=a1.z; aS[7]=a1.w;
    const float4* pb = (const float4*)(bShift + lane * 8);
    const float4 c0 = pb[0], c1 = pb[1];
    bS[0]=c0.x; bS[1]=c0.y; bS[2]=c0.z; bS[3]=c0.w;
    bS[4]=c1.x; bS[5]=c1.y; bS[6]=c1.z; bS[7]=c1.w;
    const u16x8 us = *(const u16x8*)(agg + (size_t)node * HC + lane * 8);
    #pragma unroll
    for (int c = 0; c < 8; ++c)
      ys[c] = fmaxf(0.f, bf2f((ushort)us[c]) * aS[c] + bS[c]);
  }
  const int* pt = csr_t + start;
  const int* pe = csr_eid + start;
  auto row = [&](int idx) {
    return *(const u16x8*)(agg + (size_t)pt[idx] * HC + lane * 8);
  };
  auto emit = [&](const u16x8 ut, int eid) {
    float s = 0.f;
    #pragma unroll
    for (int c = 0; c < 8; ++c)
      s += ys[c] * fmaxf(0.f, bf2f((ushort)ut[c]) * aS[c] + bS[c]);
    #pragma unroll
    for (int off = 32; off > 0; off >>= 1) s += __shfl_down(s, off, 64);
    if (lane == 0) out[eid] = s;
  };
  u16x8 b0 = {}, b1 = {};
  b0 = row(0);
  if (deg > 1) b1 = row(1);
  int j = 0;
  for (; j + 2 <= deg; j += 2) {
    const u16x8 c0 = b0;
    if (j + 2 < deg) b0 = row(j + 2);
    const u16x8 c1 = b1;
    if (j + 3 < deg) b1 = row(j + 3);
    emit(c0, pe[j]);
    emit(c1, pe[j + 1]);
  }
  if (j < deg) emit(b0, pe[j]);
}

extern "C" void kernel_launch(void* const* d_in, const int* in_sizes, int n_in,
                              void* d_out, int out_size, void* d_ws, size_t ws_size,
                              hipStream_t stream) {
  const float* x     = (const float*)d_in[0];
  const int*   ei    = (const int*)d_in[1];
  const int*   eli   = (const int*)d_in[2];
  const float* W_l   = (const float*)d_in[3];
  const float* W_r   = (const float*)d_in[4];
  const float* att   = (const float*)d_in[5];
  // d_in[6] = bias: cancels exactly inside train-mode BatchNorm -> unused.
  const float* gamma = (const float*)d_in[7];
  const float* beta  = (const float*)d_in[8];
  float* out = (float*)d_out;

  const int Nn = in_sizes[0] / IN_CH;  // 20000
  const int E  = in_sizes[1] / 2;      // 320000
  const int EL = in_sizes[2] / 2;      // 100000

  // ---- workspace layout ----
  ushort* xlb = (ushort*)d_ws;                     // Nn*HC bf16
  ushort* xrb = xlb + (size_t)Nn * HC;             // Nn*HC bf16 (reused as agg)
  ushort* xbf = xrb + (size_t)Nn * HC;             // Nn*IN_CH bf16
  ushort* btb = xbf + (size_t)Nn * IN_CH;          // NPACK*IN_CH bf16
  int* counts   = (int*)(btb + (size_t)NPACK * IN_CH);  // Nn ┐
  int* counts2  = counts + Nn;                          // Nn │ single
  float* gsum   = (float*)(counts2 + Nn);               // HC │ memset
  float* gsq    = gsum + HC;                            // HC │ region
  int* flagsA   = (int*)(gsq + HC);                     // 128│
  int* flagsB   = flagsA + 128;                         // 128│
  int* bnctr    = flagsB + 128;                         // 64 ┘ (padded)
  int* offsets  = bnctr + 64;           // Nn
  int* cursor   = offsets + Nn;         // Nn
  int* offsets2 = cursor + Nn;          // Nn
  int* cursor2  = offsets2 + Nn;        // Nn
  int* csr_src  = cursor2 + Nn;         // E
  int* csr_t    = csr_src + E;          // EL
  int* csr_eid  = csr_t + EL;           // EL
  float* aScale = (float*)(csr_eid + EL);  // HC
  float* bShift = aScale + HC;             // HC
  ushort* agg = xrb;

  const int nb  = (Nn + 255) / 256;           // scan blocks per CSR (79)
  const int nbc = (Nn * IN_CH / 4 + 255) / 256;
  const int nbp = (NPACK * IN_CH + 255) / 256;
  const int nbh = (E + 255) / 256;
  const int nbh2 = (EL + 255) / 256;

  // 0) one memset: counts | counts2 | gsum | gsq | flagsA | flagsB | bnctr
  (void)hipMemsetAsync(counts, 0, (2 * (size_t)Nn + 2 * HC + 320) * sizeof(int), stream);

  // 1) fused prep: cast + pack + both histograms
  prep<<<nbc + nbp + nbh + nbh2, 256, 0, stream>>>(
      x, xbf, W_l, W_r, btb, ei, counts, eli, counts2,
      Nn * IN_CH / 4, E, EL, nbc, nbp, nbh);

  // 2) one bf16 MFMA GEMM -> xlb | xrb
  dim3 ggrid(NPACK / 128, (Nn + 127) / 128);
  gemm_mfma<<<ggrid, 256, 0, stream>>>(xbf, btb, xlb, xrb, Nn);

  // 3) fused dual-CSR scan (lookback) + separate wide fill (R10-proven split)
  scan_fused<<<2 * nb, 256, 0, stream>>>(counts, offsets, cursor, flagsA,
                                         counts2, offsets2, cursor2, flagsB, Nn, nb);
  csr_fill<<<nbh + nbh2, 256, 0, stream>>>(ei, cursor, csr_src,
                                           eli, cursor2, csr_t, csr_eid, E, EL, nbh);

  // 4) fused attention + softmax + aggregation (1 wave/node, no atomics)
  gatv2_agg<<<(Nn + 3) / 4, 256, 0, stream>>>(xlb, xrb, att, offsets, counts,
                                              csr_src, agg, Nn);

  // 5) BN stats + last-block finalize -> aScale/bShift
  bn_stats<<<200, 256, 0, stream>>>(agg, gsum, gsq, bnctr, gamma, beta,
                                    aScale, bShift, 1.0f / (float)Nn, Nn);

  // 6) source-grouped link scoring with inline BN+ReLU
  score_g<<<(Nn + 3) / 4, 256, 0, stream>>>(agg, aScale, bShift, offsets2,
                                            counts2, csr_t, csr_eid, out, Nn);
}